// Round 3
// baseline (1347.799 us; speedup 1.0000x reference)
//
#include <hip/hip_runtime.h>
#include <hip/hip_bf16.h>

#define CI 32
#define CO 32
#define WIN 256            // output rows per owned window
#define ACC_STRIDE 36      // padded f32 stride: 16B-aligned vec4, 2-way-free ds_add banks

typedef unsigned int u32;
typedef unsigned long long u64;
typedef __attribute__((ext_vector_type(8))) short bf16x8;
typedef __attribute__((ext_vector_type(4))) float f32x4;

__device__ inline short f2bf(float x) {
    __hip_bfloat16 h = __float2bfloat16(x);
    return *reinterpret_cast<short*>(&h);
}

// ---------------- sort machinery ----------------

__global__ void fill_u32_kernel(u32* __restrict__ p, u32 v, size_t n) {
    size_t i = (size_t)blockIdx.x * blockDim.x + threadIdx.x;
    size_t stride = (size_t)gridDim.x * blockDim.x;
    for (; i < n; i += stride) p[i] = v;
}

__global__ void hist_kernel(const int* __restrict__ out_map, u32* __restrict__ cnt,
                            int P, int K) {
    int k = blockIdx.y;
    int i = blockIdx.x * blockDim.x + threadIdx.x;
    if (i >= P) return;
    u32 o = (u32)out_map[(size_t)k * P + i];
    atomicAdd(&cnt[(o >> 8) * (u32)K + (u32)k], 1u);   // 211KB counter array: L2-resident
}

// single-block exclusive scan of padded counts (NB ~= 53K): off, cursor, off[NB]=total
__global__ void scan_kernel(const u32* __restrict__ cnt, u32* __restrict__ off,
                            u32* __restrict__ cursor, int NB) {
    __shared__ u32 ts[1024];
    int t = threadIdx.x;
    int ipt = (NB + 1023) >> 10;
    int s = t * ipt;
    u32 sum = 0;
    for (int i = 0; i < ipt; ++i) {
        int j = s + i;
        if (j < NB) sum += (cnt[j] + 15u) & ~15u;      // pad each segment to x16
    }
    ts[t] = sum;
    __syncthreads();
    for (int d = 1; d < 1024; d <<= 1) {
        u32 v = 0;
        if (t >= d) v = ts[t - d];
        __syncthreads();
        ts[t] += v;
        __syncthreads();
    }
    u32 run = (t == 0) ? 0u : ts[t - 1];
    for (int i = 0; i < ipt; ++i) {
        int j = s + i;
        if (j < NB) {
            off[j] = run;
            cursor[j] = run;
            run += (cnt[j] + 15u) & ~15u;
        }
    }
    if (t == 1023) off[NB] = ts[1023];
}

// pairs[pos] = (o << 32) | (k << 22) | flat    (flat = k*P+p < 2^22, k < 32)
__global__ void scatter_kernel(const int* __restrict__ out_map, u32* __restrict__ cursor,
                               u64* __restrict__ pairs, int P, int K) {
    int k = blockIdx.y;
    int i = blockIdx.x * blockDim.x + threadIdx.x;
    if (i >= P) return;
    u32 flat = (u32)k * (u32)P + (u32)i;
    u32 o = (u32)out_map[(size_t)k * P + i];
    u32 b = (o >> 8) * (u32)K + (u32)k;
    u32 pos = atomicAdd(&cursor[b], 1u);
    pairs[pos] = ((u64)o << 32) | ((u32)(k << 22) | flat);
}

// ---------------- main compute: window-owner, MFMA, LDS accumulate ----------------

__global__ __launch_bounds__(512, 4) void window_conv_kernel(
    const float* __restrict__ features,
    const float* __restrict__ weight,
    const float* __restrict__ bias,
    const int* __restrict__ in_map,
    const u64* __restrict__ pairs,
    const u32* __restrict__ off,
    float* __restrict__ out,
    int K, int num_out)
{
    __shared__ float acc[WIN * ACC_STRIDE];
    const int tid = threadIdx.x;

    #pragma unroll
    for (int i = 0; i < (WIN * ACC_STRIDE) / 512; ++i)
        acc[tid + i * 512] = 0.f;
    __syncthreads();

    const int w = blockIdx.x;
    const int wid = tid >> 6;          // 0..7
    const int lane = tid & 63;
    const int q = lane >> 4;
    const int m = lane & 15;

    const u32 start = off[w * K];
    const u32 end   = off[w * K + K];
    const int nG = (int)((end - start) >> 4);
    const u32* hiPtr = (const u32*)pairs;

    for (int g = wid; g < nG; g += 8) {
        const u32 slot = start + (u32)g * 16u;
        const u64 pr = pairs[slot + m];
        const u32 lo = (u32)pr;
        const u32 flat = lo & 0x3FFFFFu;

        const u32 lo0 = __builtin_amdgcn_readfirstlane(lo);
        if ((lo0 & 0x3FFFFFu) == 0x3FFFFFu) continue;      // all-pad group
        const int kk = (int)((lo0 >> 22) & 31u);           // wave-uniform k
        const float* __restrict__ wk = weight + (size_t)kk * (CI * CO);

        const bool valid = flat != 0x3FFFFFu;
        const int r = valid ? in_map[flat] : 0;

        // A: lane holds feature row r, k-cols q*8..q*8+7
        const f32x4* frow = (const f32x4*)(features + (size_t)r * CI + q * 8);
        f32x4 v0 = frow[0];
        f32x4 v1 = frow[1];
        bf16x8 a;
        a[0]=f2bf(v0.x); a[1]=f2bf(v0.y); a[2]=f2bf(v0.z); a[3]=f2bf(v0.w);
        a[4]=f2bf(v1.x); a[5]=f2bf(v1.y); a[6]=f2bf(v1.z); a[7]=f2bf(v1.w);
        if (!valid) a = (bf16x8){0,0,0,0,0,0,0,0};

        // B: wave-uniform base + lane offsets (L2-hot, 110KB total weights)
        bf16x8 b0, b1;
        #pragma unroll
        for (int j = 0; j < 8; ++j) {
            int kc = q * 8 + j;
            b0[j] = f2bf(wk[kc * CO + m]);
            b1[j] = f2bf(wk[kc * CO + 16 + m]);
        }

        f32x4 acc0 = {0.f,0.f,0.f,0.f};
        f32x4 acc1 = {0.f,0.f,0.f,0.f};
        acc0 = __builtin_amdgcn_mfma_f32_16x16x32_bf16(a, b0, acc0, 0, 0, 0);
        acc1 = __builtin_amdgcn_mfma_f32_16x16x32_bf16(a, b1, acc1, 0, 0, 0);

        // accumulate into owned LDS window (ds_add_f32; bank-spread via stride 36)
        #pragma unroll
        for (int j = 0; j < 4; ++j) {
            const u32 erow = slot + (u32)(q * 4 + j);
            const u32 oj = hiPtr[erow * 2 + 1];            // hi word = o (pad = 0xFFFFFFFF)
            if (oj != 0xFFFFFFFFu) {
                const int lr = (int)(oj & (WIN - 1));
                atomicAdd(&acc[lr * ACC_STRIDE + m],      acc0[j]);
                atomicAdd(&acc[lr * ACC_STRIDE + 16 + m], acc1[j]);
            }
        }
    }
    __syncthreads();

    // write window once: out = acc + bias  (coalesced vec4 stores)
    #pragma unroll
    for (int i = 0; i < 4; ++i) {
        const int v = tid + i * 512;       // 0..2047
        const int row = v >> 3;
        const int c4 = v & 7;
        const int o = w * WIN + row;
        if (o < num_out) {
            f32x4 val = *(const f32x4*)&acc[row * ACC_STRIDE + c4 * 4];
            f32x4 bs = ((const f32x4*)bias)[c4];
            val.x += bs.x; val.y += bs.y; val.z += bs.z; val.w += bs.w;
            ((f32x4*)out)[(size_t)o * 8 + c4] = val;
        }
    }
}

// ---------------- fallback (R2 path) if workspace too small ----------------

__global__ void bias_init_kernel(float* __restrict__ out, const float* __restrict__ bias,
                                 int total4) {
    int idx = blockIdx.x * blockDim.x + threadIdx.x;
    if (idx >= total4) return;
    ((float4*)out)[idx] = ((const float4*)bias)[idx & 7];
}

__global__ __launch_bounds__(256, 8) void scatter_conv_mfma(
    const float* __restrict__ features, const float* __restrict__ weight,
    const int* __restrict__ in_map, const int* __restrict__ out_map,
    float* __restrict__ out, int P, int groups)
{
    const int k = blockIdx.y;
    const size_t kP = (size_t)k * (size_t)P;
    const int lane = threadIdx.x & 63;
    const int q = lane >> 4;
    const int m = lane & 15;
    const float* __restrict__ wk = weight + (size_t)k * (CI * CO);
    bf16x8 b0, b1;
    #pragma unroll
    for (int j = 0; j < 8; ++j) {
        int kk = q * 8 + j;
        b0[j] = f2bf(wk[kk * CO + m]);
        b1[j] = f2bf(wk[kk * CO + 16 + m]);
    }
    const int gwave = (blockIdx.x * blockDim.x + threadIdx.x) >> 6;
    const int gstride = (gridDim.x * blockDim.x) >> 6;
    for (int g = gwave; g < groups; g += gstride) {
        const int pbase = g * 16;
        const int pm = pbase + m;
        const int r = (pm < P) ? in_map[kP + pm] : 0;
        const f32x4* frow = (const f32x4*)(features + (size_t)r * CI + q * 8);
        f32x4 v0 = frow[0];
        f32x4 v1 = frow[1];
        bf16x8 a;
        a[0]=f2bf(v0.x); a[1]=f2bf(v0.y); a[2]=f2bf(v0.z); a[3]=f2bf(v0.w);
        a[4]=f2bf(v1.x); a[5]=f2bf(v1.y); a[6]=f2bf(v1.z); a[7]=f2bf(v1.w);
        if (pm >= P) a = (bf16x8){0,0,0,0,0,0,0,0};
        f32x4 acc0 = {0.f,0.f,0.f,0.f};
        f32x4 acc1 = {0.f,0.f,0.f,0.f};
        acc0 = __builtin_amdgcn_mfma_f32_16x16x32_bf16(a, b0, acc0, 0, 0, 0);
        acc1 = __builtin_amdgcn_mfma_f32_16x16x32_bf16(a, b1, acc1, 0, 0, 0);
        #pragma unroll
        for (int j = 0; j < 4; ++j) {
            const int row = q * 4 + j;
            const int pr = pbase + row;
            if (pr < P) {
                const int o = out_map[kP + pr];
                float* base = out + (size_t)o * CO + m;
                unsafeAtomicAdd(base,      acc0[j]);
                unsafeAtomicAdd(base + 16, acc1[j]);
            }
        }
    }
}

// ---------------- launch ----------------

static inline size_t align256(size_t x) { return (x + 255) & ~(size_t)255; }

extern "C" void kernel_launch(void* const* d_in, const int* in_sizes, int n_in,
                              void* d_out, int out_size, void* d_ws, size_t ws_size,
                              hipStream_t stream) {
    const float* features = (const float*)d_in[0];
    const float* weight   = (const float*)d_in[1];
    const float* bias     = (const float*)d_in[2];
    const int*   in_map   = (const int*)d_in[3];
    const int*   out_map  = (const int*)d_in[4];

    const int K = in_sizes[1] / (CI * CO);           // 27
    const int P = in_sizes[3] / K;                   // 150000
    const int num_out = out_size / CO;               // 500000
    float* out = (float*)d_out;

    const size_t NBW = ((size_t)num_out + WIN - 1) / WIN;     // 1954 windows
    const size_t NB = NBW * (size_t)K;                        // 52758 buckets
    const size_t total = (size_t)K * (size_t)P;               // 4.05M entries
    const size_t CAP = total + 15 * NB;                       // padded slot capacity

    const size_t o_cnt = 0;
    const size_t o_off = align256(o_cnt + NB * 4);
    const size_t o_cur = align256(o_off + (NB + 1) * 4);
    const size_t o_pairs = align256(o_cur + NB * 4);
    const size_t need = o_pairs + CAP * 8;

    const bool sortable = (ws_size >= need) && (K <= 32) && (total < (1u << 22));

    if (!sortable) {
        // fallback: R2 gather-MFMA-global-atomic path
        int total4 = num_out * (CO / 4);
        hipLaunchKernelGGL(bias_init_kernel, dim3((total4 + 255) / 256), dim3(256), 0,
                           stream, out, bias, total4);
        const int groups = (P + 15) / 16;
        hipLaunchKernelGGL(scatter_conv_mfma, dim3(160, K), dim3(256), 0, stream,
                           features, weight, in_map, out_map, out, P, groups);
        return;
    }

    char* ws = (char*)d_ws;
    u32* cnt    = (u32*)(ws + o_cnt);
    u32* off    = (u32*)(ws + o_off);
    u32* cursor = (u32*)(ws + o_cur);
    u64* pairs  = (u64*)(ws + o_pairs);

    // 1) zero counters; sentinel-fill sorted pairs (deterministic every call)
    hipLaunchKernelGGL(fill_u32_kernel, dim3(64), dim3(256), 0, stream, cnt, 0u, NB);
    hipLaunchKernelGGL(fill_u32_kernel, dim3(2048), dim3(256), 0, stream,
                       (u32*)pairs, 0xFFFFFFFFu, CAP * 2);

    // 2) histogram by (window, k)
    dim3 mgrid((P + 255) / 256, K);
    hipLaunchKernelGGL(hist_kernel, mgrid, dim3(256), 0, stream, out_map, cnt, P, K);

    // 3) exclusive scan of padded counts (single block)
    hipLaunchKernelGGL(scan_kernel, dim3(1), dim3(1024), 0, stream, cnt, off, cursor, (int)NB);

    // 4) scatter packed (o, k, flat) pairs into bucket segments
    hipLaunchKernelGGL(scatter_kernel, mgrid, dim3(256), 0, stream, out_map, cursor, pairs, P, K);

    // 5) window-owner compute: MFMA + LDS-accumulate + single coalesced write
    hipLaunchKernelGGL(window_conv_kernel, dim3((u32)NBW), dim3(512), 0, stream,
                       features, weight, bias, in_map, pairs, off, out, K, num_out);
}

// Round 4
// 1127.761 us; speedup vs baseline: 1.1951x; 1.1951x over previous
//
#include <hip/hip_runtime.h>
#include <hip/hip_bf16.h>

#define CI 32
#define CO 32
#define WIN 256            // output rows per owned window
#define ACC_STRIDE 36      // padded f32 stride for LDS accumulator

typedef unsigned int u32;
typedef unsigned long long u64;
typedef __attribute__((ext_vector_type(8))) short bf16x8;
typedef __attribute__((ext_vector_type(4))) float f32x4;

#define SENT 0xFFFFFFFFu
#define INR_MASK 0x7FFFFu   // 19-bit in_row field; 0x7FFFF = invalid sentinel

__device__ inline short f2bf(float x) {
    __hip_bfloat16 h = __float2bfloat16(x);
    return *reinterpret_cast<short*>(&h);
}

// ---------------- prep kernels ----------------

__global__ void fill_u32_kernel(u32* __restrict__ p, u32 v, size_t n) {
    size_t i = (size_t)blockIdx.x * blockDim.x + threadIdx.x;
    size_t stride = (size_t)gridDim.x * blockDim.x;
    for (; i < n; i += stride) p[i] = v;
}

// features fp32 -> bf16 (rows become one 64B line each)
__global__ void convert_features(const float* __restrict__ f, short* __restrict__ fb,
                                 size_t n8) {   // n8 = total_elems/8
    size_t i = (size_t)blockIdx.x * blockDim.x + threadIdx.x;
    size_t stride = (size_t)gridDim.x * blockDim.x;
    for (; i < n8; i += stride) {
        const f32x4* src = (const f32x4*)(f + i * 8);
        f32x4 v0 = src[0], v1 = src[1];
        bf16x8 o;
        o[0]=f2bf(v0.x); o[1]=f2bf(v0.y); o[2]=f2bf(v0.z); o[3]=f2bf(v0.w);
        o[4]=f2bf(v1.x); o[5]=f2bf(v1.y); o[6]=f2bf(v1.z); o[7]=f2bf(v1.w);
        ((bf16x8*)fb)[i] = o;
    }
}

// weights -> MFMA B-frag order: wp[((k*64+lane)*2+h)*8 + j] = bf16(W[k][q*8+j][h*16+m])
__global__ void prepack_weights(const float* __restrict__ w, short* __restrict__ wp, int K) {
    int t = blockIdx.x * blockDim.x + threadIdx.x;
    if (t >= K * 128) return;
    int h = t & 1, lane = (t >> 1) & 63, k = t >> 7;
    int q = lane >> 4, m = lane & 15;
    bf16x8 v;
    #pragma unroll
    for (int j = 0; j < 8; ++j)
        v[j] = f2bf(w[k * (CI*CO) + (q*8 + j) * CO + h*16 + m]);
    ((bf16x8*)wp)[t] = v;
}

// ---------------- sort machinery ----------------

__global__ void hist_kernel(const int* __restrict__ out_map, u32* __restrict__ cnt,
                            int P, int K) {
    int k = blockIdx.y;
    int i = blockIdx.x * blockDim.x + threadIdx.x;
    if (i >= P) return;
    u32 o = (u32)out_map[(size_t)k * P + i];
    atomicAdd(&cnt[(o >> 8) * (u32)K + (u32)k], 1u);
}

// phase A: per-256 block local exclusive scan of padded counts
__global__ void scan_local(const u32* __restrict__ cnt, u32* __restrict__ off,
                           u32* __restrict__ bsum, int NB) {
    __shared__ u32 s[256];
    int t = threadIdx.x;
    int i = blockIdx.x * 256 + t;
    u32 pc = (i < NB) ? ((cnt[i] + 15u) & ~15u) : 0u;
    s[t] = pc; __syncthreads();
    #pragma unroll
    for (int d = 1; d < 256; d <<= 1) {
        u32 v = (t >= d) ? s[t - d] : 0u;
        __syncthreads();
        s[t] += v;
        __syncthreads();
    }
    if (i < NB) off[i] = s[t] - pc;          // exclusive
    if (t == 255) bsum[blockIdx.x] = s[255];
}

// phase B: single block scans block sums; writes grand total to off[NB]
__global__ void scan_bsum(u32* __restrict__ bsum, u32* __restrict__ off,
                          int nblk, int NB) {
    __shared__ u32 s[256];
    int t = threadIdx.x;
    u32 v = (t < nblk) ? bsum[t] : 0u;
    s[t] = v; __syncthreads();
    #pragma unroll
    for (int d = 1; d < 256; d <<= 1) {
        u32 x = (t >= d) ? s[t - d] : 0u;
        __syncthreads();
        s[t] += x;
        __syncthreads();
    }
    if (t < nblk) bsum[t] = s[t] - v;        // exclusive
    if (t == 255) off[NB] = s[255];          // grand total
}

// phase C: add block offsets; init cursor
__global__ void scan_add(u32* __restrict__ off, u32* __restrict__ cursor,
                         const u32* __restrict__ bsum, int NB) {
    int i = blockIdx.x * blockDim.x + threadIdx.x;
    if (i < NB) {
        u32 o = off[i] + bsum[i >> 8];
        off[i] = o;
        cursor[i] = o;
    }
}

// scatter compact payload: (o&255)<<24 | k<<19 | in_row
__global__ void scatter_kernel(const int* __restrict__ out_map,
                               const int* __restrict__ in_map,
                               u32* __restrict__ cursor, u32* __restrict__ pairs,
                               int P, int K) {
    int k = blockIdx.y;
    int i = blockIdx.x * blockDim.x + threadIdx.x;
    if (i >= P) return;
    size_t idx = (size_t)k * P + i;
    u32 o   = (u32)out_map[idx];
    u32 inr = (u32)in_map[idx];
    u32 b = (o >> 8) * (u32)K + (u32)k;
    u32 pos = atomicAdd(&cursor[b], 1u);
    pairs[pos] = ((o & 255u) << 24) | ((u32)k << 19) | inr;
}

// sentinel-fill only the pad slots (~3 MB, not 260 MB)
__global__ void padfill_kernel(const u32* __restrict__ cnt, const u32* __restrict__ off,
                               u32* __restrict__ pairs, int NB) {
    int b = blockIdx.x * blockDim.x + threadIdx.x;
    if (b >= NB) return;
    u32 s = off[b] + cnt[b];
    u32 e = off[b + 1];
    for (u32 x = s; x < e; ++x) pairs[x] = SENT;
}

// ---------------- main compute: window-owner, MFMA, LDS accumulate ----------------

__global__ __launch_bounds__(512, 4) void window_conv_kernel(
    const short* __restrict__ fb16,    // [num_in*32] bf16
    const short* __restrict__ wpack,   // [32*64*16] bf16 frag-order
    const float* __restrict__ bias,
    const u32* __restrict__ pairs,
    const u32* __restrict__ off,
    float* __restrict__ out,
    int K, int num_out)
{
    __shared__ float acc[WIN * ACC_STRIDE];
    const int tid = threadIdx.x;
    #pragma unroll
    for (int i = 0; i < (WIN * ACC_STRIDE) / 512; ++i)
        acc[tid + i * 512] = 0.f;
    __syncthreads();

    const int w = blockIdx.x;
    const int wid = tid >> 6;
    const int lane = tid & 63;
    const int q = lane >> 4;
    const int m = lane & 15;

    const u32 start = off[w * K];
    const u32 end   = off[w * K + K];
    const int nG = (int)((end - start) >> 4);
    const u32* __restrict__ pb = pairs + start;

    // 2-deep pair prefetch + 1-deep feature prefetch
    u32 pr0 = (wid     < nG) ? pb[(u32)wid * 16u + m]       : SENT;
    u32 pr1 = (wid + 8 < nG) ? pb[(u32)(wid + 8) * 16u + m] : SENT;
    u32 inr0 = ((pr0 & INR_MASK) != INR_MASK) ? (pr0 & INR_MASK) : 0u;
    bf16x8 a0 = *(const bf16x8*)(fb16 + (size_t)inr0 * 32 + q * 8);

    int kprev = -1;
    bf16x8 b0 = {}, b1 = {};

    for (int g = wid; g < nG; g += 8) {
        // prefetch next-next pair and next feature row
        u32 pr2 = (g + 16 < nG) ? pb[(u32)(g + 16) * 16u + m] : SENT;
        u32 inr1 = ((pr1 & INR_MASK) != INR_MASK) ? (pr1 & INR_MASK) : 0u;
        bf16x8 a1 = *(const bf16x8*)(fb16 + (size_t)inr1 * 32 + q * 8);

        // process current group
        const u32 h = __builtin_amdgcn_readfirstlane(pr0);
        const int kk = (int)((h >> 19) & 31u);        // wave-uniform (bucket-pure groups)
        if (kk != kprev) {                             // ~80% of iters reuse B
            const bf16x8* wb = (const bf16x8*)wpack + ((size_t)kk * 64 + lane) * 2;
            b0 = wb[0]; b1 = wb[1];
            kprev = kk;
        }

        bf16x8 az = a0;
        if ((pr0 & INR_MASK) == INR_MASK) az = (bf16x8){0,0,0,0,0,0,0,0};

        f32x4 c0 = {0.f,0.f,0.f,0.f};
        f32x4 c1 = {0.f,0.f,0.f,0.f};
        c0 = __builtin_amdgcn_mfma_f32_16x16x32_bf16(az, b0, c0, 0, 0, 0);
        c1 = __builtin_amdgcn_mfma_f32_16x16x32_bf16(az, b1, c1, 0, 0, 0);

        // scatter D rows (entry q*4+j) into owned LDS window
        #pragma unroll
        for (int j = 0; j < 4; ++j) {
            u32 prj = __shfl(pr0, q * 4 + j);
            if ((prj & INR_MASK) != INR_MASK) {
                int lr = (int)(prj >> 24);
                atomicAdd(&acc[lr * ACC_STRIDE + m],      c0[j]);
                atomicAdd(&acc[lr * ACC_STRIDE + 16 + m], c1[j]);
            }
        }

        pr0 = pr1; pr1 = pr2; a0 = a1;
    }
    __syncthreads();

    // write window once: out = acc + bias
    #pragma unroll
    for (int i = 0; i < 4; ++i) {
        const int v = tid + i * 512;
        const int row = v >> 3;
        const int c4 = v & 7;
        const int o = w * WIN + row;
        if (o < num_out) {
            f32x4 val = *(const f32x4*)&acc[row * ACC_STRIDE + c4 * 4];
            f32x4 bs = ((const f32x4*)bias)[c4];
            val.x += bs.x; val.y += bs.y; val.z += bs.z; val.w += bs.w;
            ((f32x4*)out)[(size_t)o * 8 + c4] = val;
        }
    }
}

// ---------------- fallback (R2 path) ----------------

__global__ void bias_init_kernel(float* __restrict__ out, const float* __restrict__ bias,
                                 int total4) {
    int idx = blockIdx.x * blockDim.x + threadIdx.x;
    if (idx >= total4) return;
    ((float4*)out)[idx] = ((const float4*)bias)[idx & 7];
}

__global__ __launch_bounds__(256, 8) void scatter_conv_mfma(
    const float* __restrict__ features, const float* __restrict__ weight,
    const int* __restrict__ in_map, const int* __restrict__ out_map,
    float* __restrict__ out, int P, int groups)
{
    const int k = blockIdx.y;
    const size_t kP = (size_t)k * (size_t)P;
    const int lane = threadIdx.x & 63;
    const int q = lane >> 4;
    const int m = lane & 15;
    const float* __restrict__ wk = weight + (size_t)k * (CI * CO);
    bf16x8 b0, b1;
    #pragma unroll
    for (int j = 0; j < 8; ++j) {
        int kk = q * 8 + j;
        b0[j] = f2bf(wk[kk * CO + m]);
        b1[j] = f2bf(wk[kk * CO + 16 + m]);
    }
    const int gwave = (blockIdx.x * blockDim.x + threadIdx.x) >> 6;
    const int gstride = (gridDim.x * blockDim.x) >> 6;
    for (int g = gwave; g < groups; g += gstride) {
        const int pbase = g * 16;
        const int pm = pbase + m;
        const int r = (pm < P) ? in_map[kP + pm] : 0;
        const f32x4* frow = (const f32x4*)(features + (size_t)r * CI + q * 8);
        f32x4 v0 = frow[0];
        f32x4 v1 = frow[1];
        bf16x8 a;
        a[0]=f2bf(v0.x); a[1]=f2bf(v0.y); a[2]=f2bf(v0.z); a[3]=f2bf(v0.w);
        a[4]=f2bf(v1.x); a[5]=f2bf(v1.y); a[6]=f2bf(v1.z); a[7]=f2bf(v1.w);
        if (pm >= P) a = (bf16x8){0,0,0,0,0,0,0,0};
        f32x4 acc0 = {0.f,0.f,0.f,0.f};
        f32x4 acc1 = {0.f,0.f,0.f,0.f};
        acc0 = __builtin_amdgcn_mfma_f32_16x16x32_bf16(a, b0, acc0, 0, 0, 0);
        acc1 = __builtin_amdgcn_mfma_f32_16x16x32_bf16(a, b1, acc1, 0, 0, 0);
        #pragma unroll
        for (int j = 0; j < 4; ++j) {
            const int row = q * 4 + j;
            const int pr = pbase + row;
            if (pr < P) {
                const int o = out_map[kP + pr];
                float* base = out + (size_t)o * CO + m;
                unsafeAtomicAdd(base,      acc0[j]);
                unsafeAtomicAdd(base + 16, acc1[j]);
            }
        }
    }
}

// ---------------- launch ----------------

static inline size_t align256(size_t x) { return (x + 255) & ~(size_t)255; }

extern "C" void kernel_launch(void* const* d_in, const int* in_sizes, int n_in,
                              void* d_out, int out_size, void* d_ws, size_t ws_size,
                              hipStream_t stream) {
    const float* features = (const float*)d_in[0];
    const float* weight   = (const float*)d_in[1];
    const float* bias     = (const float*)d_in[2];
    const int*   in_map   = (const int*)d_in[3];
    const int*   out_map  = (const int*)d_in[4];

    const int K = in_sizes[1] / (CI * CO);           // 27
    const int P = in_sizes[3] / K;                   // 150000
    const int num_out = out_size / CO;               // 500000
    const int num_in  = in_sizes[0] / CI;            // 500000
    float* out = (float*)d_out;

    const size_t NBW = ((size_t)num_out + WIN - 1) / WIN;     // windows
    const size_t NB  = NBW * (size_t)K;                       // buckets
    const size_t total = (size_t)K * (size_t)P;
    const size_t CAP = total + 15 * NB;
    const int nblkA = (int)((NB + 255) / 256);

    // ws layout
    const size_t o_cnt   = 0;
    const size_t o_off   = align256(o_cnt + NB * 4);
    const size_t o_cur   = align256(o_off + (NB + 1) * 4);
    const size_t o_bsum  = align256(o_cur + NB * 4);
    const size_t o_pairs = align256(o_bsum + 256 * 4);
    const size_t o_fb16  = align256(o_pairs + CAP * 4);
    const size_t o_wpack = align256(o_fb16 + (size_t)num_in * CI * 2);
    const size_t need    = o_wpack + (size_t)32 * 64 * 16 * 2;

    const bool sortable = (ws_size >= need) && (K <= 31) &&
                          (num_in <= 0x7FFFE) && (nblkA <= 256);

    if (!sortable) {
        int total4 = num_out * (CO / 4);
        hipLaunchKernelGGL(bias_init_kernel, dim3((total4 + 255) / 256), dim3(256), 0,
                           stream, out, bias, total4);
        const int groups = (P + 15) / 16;
        hipLaunchKernelGGL(scatter_conv_mfma, dim3(160, K), dim3(256), 0, stream,
                           features, weight, in_map, out_map, out, P, groups);
        return;
    }

    char* ws = (char*)d_ws;
    u32*   cnt    = (u32*)(ws + o_cnt);
    u32*   off    = (u32*)(ws + o_off);
    u32*   cursor = (u32*)(ws + o_cur);
    u32*   bsum   = (u32*)(ws + o_bsum);
    u32*   pairs  = (u32*)(ws + o_pairs);
    short* fb16   = (short*)(ws + o_fb16);
    short* wpack  = (short*)(ws + o_wpack);

    // prep (independent)
    hipLaunchKernelGGL(fill_u32_kernel, dim3(64), dim3(256), 0, stream, cnt, 0u, NB);
    hipLaunchKernelGGL(convert_features, dim3(1024), dim3(256), 0, stream,
                       features, fb16, (size_t)num_in * CI / 8);
    hipLaunchKernelGGL(prepack_weights, dim3((K * 128 + 255) / 256), dim3(256), 0, stream,
                       weight, wpack, K);

    // counting sort by (window, k)
    dim3 mgrid((P + 255) / 256, K);
    hipLaunchKernelGGL(hist_kernel, mgrid, dim3(256), 0, stream, out_map, cnt, P, K);
    hipLaunchKernelGGL(scan_local, dim3(nblkA), dim3(256), 0, stream, cnt, off, bsum, (int)NB);
    hipLaunchKernelGGL(scan_bsum, dim3(1), dim3(256), 0, stream, bsum, off, nblkA, (int)NB);
    hipLaunchKernelGGL(scan_add, dim3(nblkA), dim3(256), 0, stream, off, cursor, bsum, (int)NB);
    hipLaunchKernelGGL(scatter_kernel, mgrid, dim3(256), 0, stream,
                       out_map, in_map, cursor, pairs, P, K);
    hipLaunchKernelGGL(padfill_kernel, dim3(nblkA), dim3(256), 0, stream,
                       cnt, off, pairs, (int)NB);

    // compute
    hipLaunchKernelGGL(window_conv_kernel, dim3((u32)NBW), dim3(512), 0, stream,
                       fb16, wpack, bias, pairs, off, out, K, num_out);
}

// Round 5
// 1125.539 us; speedup vs baseline: 1.1975x; 1.0020x over previous
//
#include <hip/hip_runtime.h>
#include <hip/hip_bf16.h>

#define CI 32
#define CO 32
#define WIN 256            // output rows per owned window
#define ACC_STRIDE 36      // padded f32 stride for LDS accumulator

typedef unsigned int u32;
typedef unsigned long long u64;
typedef __attribute__((ext_vector_type(8))) short bf16x8;
typedef __attribute__((ext_vector_type(4))) float f32x4;

#define INR_MASK 0x7FFFFu   // 19-bit in_row field
#define KPAD 31u            // k-field pad marker

__device__ inline short f2bf(float x) {
    __hip_bfloat16 h = __float2bfloat16(x);
    return *reinterpret_cast<short*>(&h);
}

// ---------------- prep kernels ----------------

__global__ void fill_u32_kernel(u32* __restrict__ p, u32 v, size_t n) {
    size_t i = (size_t)blockIdx.x * blockDim.x + threadIdx.x;
    size_t stride = (size_t)gridDim.x * blockDim.x;
    for (; i < n; i += stride) p[i] = v;
}

// features fp32 -> bf16 (rows become one 64B line each)
__global__ void convert_features(const float* __restrict__ f, short* __restrict__ fb,
                                 size_t n8) {
    size_t i = (size_t)blockIdx.x * blockDim.x + threadIdx.x;
    size_t stride = (size_t)gridDim.x * blockDim.x;
    for (; i < n8; i += stride) {
        const f32x4* src = (const f32x4*)(f + i * 8);
        f32x4 v0 = src[0], v1 = src[1];
        bf16x8 o;
        o[0]=f2bf(v0.x); o[1]=f2bf(v0.y); o[2]=f2bf(v0.z); o[3]=f2bf(v0.w);
        o[4]=f2bf(v1.x); o[5]=f2bf(v1.y); o[6]=f2bf(v1.z); o[7]=f2bf(v1.w);
        ((bf16x8*)fb)[i] = o;
    }
}

// weights -> MFMA B-frag order: wp[((k*64+lane)*2+h)*8 + j] = bf16(W[k][q*8+j][h*16+m])
__global__ void prepack_weights(const float* __restrict__ w, short* __restrict__ wp, int K) {
    int t = blockIdx.x * blockDim.x + threadIdx.x;
    if (t >= K * 128) return;
    int h = t & 1, lane = (t >> 1) & 63, k = t >> 7;
    int q = lane >> 4, m = lane & 15;
    bf16x8 v;
    #pragma unroll
    for (int j = 0; j < 8; ++j)
        v[j] = f2bf(w[k * (CI*CO) + (q*8 + j) * CO + h*16 + m]);
    ((bf16x8*)wp)[t] = v;
}

// ---------------- sort machinery ----------------

__global__ void hist_kernel(const int* __restrict__ out_map, u32* __restrict__ cnt,
                            int P, int K) {
    int k = blockIdx.y;
    int i = blockIdx.x * blockDim.x + threadIdx.x;
    if (i >= P) return;
    u32 o = (u32)out_map[(size_t)k * P + i];
    atomicAdd(&cnt[(o >> 8) * (u32)K + (u32)k], 1u);
}

// phase A: per-256 block local exclusive scan of padded counts
__global__ void scan_local(const u32* __restrict__ cnt, u32* __restrict__ off,
                           u32* __restrict__ bsum, int NB) {
    __shared__ u32 s[256];
    int t = threadIdx.x;
    int i = blockIdx.x * 256 + t;
    u32 pc = (i < NB) ? ((cnt[i] + 15u) & ~15u) : 0u;
    s[t] = pc; __syncthreads();
    #pragma unroll
    for (int d = 1; d < 256; d <<= 1) {
        u32 v = (t >= d) ? s[t - d] : 0u;
        __syncthreads();
        s[t] += v;
        __syncthreads();
    }
    if (i < NB) off[i] = s[t] - pc;          // exclusive
    if (t == 255) bsum[blockIdx.x] = s[255];
}

// phase B: single block scans block sums; writes grand total to off[NB]
__global__ void scan_bsum(u32* __restrict__ bsum, u32* __restrict__ off,
                          int nblk, int NB) {
    __shared__ u32 s[256];
    int t = threadIdx.x;
    u32 v = (t < nblk) ? bsum[t] : 0u;
    s[t] = v; __syncthreads();
    #pragma unroll
    for (int d = 1; d < 256; d <<= 1) {
        u32 x = (t >= d) ? s[t - d] : 0u;
        __syncthreads();
        s[t] += x;
        __syncthreads();
    }
    if (t < nblk) bsum[t] = s[t] - v;        // exclusive
    if (t == 255) off[NB] = s[255];          // grand total
}

// phase C: add block offsets; init cursor
__global__ void scan_add(u32* __restrict__ off, u32* __restrict__ cursor,
                         const u32* __restrict__ bsum, int NB) {
    int i = blockIdx.x * blockDim.x + threadIdx.x;
    if (i < NB) {
        u32 o = off[i] + bsum[i >> 8];
        off[i] = o;
        cursor[i] = o;
    }
}

// scatter compact payload: (o&255)<<24 | k<<19 | in_row
__global__ void scatter_kernel(const int* __restrict__ out_map,
                               const int* __restrict__ in_map,
                               u32* __restrict__ cursor, u32* __restrict__ pairs,
                               int P, int K) {
    int k = blockIdx.y;
    int i = blockIdx.x * blockDim.x + threadIdx.x;
    if (i >= P) return;
    size_t idx = (size_t)k * P + i;
    u32 o   = (u32)out_map[idx];
    u32 inr = (u32)in_map[idx];
    u32 b = (o >> 8) * (u32)K + (u32)k;
    u32 pos = atomicAdd(&cursor[b], 1u);
    pairs[pos] = ((o & 255u) << 24) | ((u32)k << 19) | inr;
}

// pad slots: k-field = KPAD (skipped), inr = 0 (safe to gather)
__global__ void padfill_kernel(const u32* __restrict__ cnt, const u32* __restrict__ off,
                               u32* __restrict__ pairs, int NB) {
    int b = blockIdx.x * blockDim.x + threadIdx.x;
    if (b >= NB) return;
    u32 s = off[b] + cnt[b];
    u32 e = off[b + 1];
    for (u32 x = s; x < e; ++x) pairs[x] = (KPAD << 19);
}

// ---------------- main compute: segment-per-wave, invariant B ----------------

__global__ __launch_bounds__(512, 6) void window_conv_kernel(
    const short* __restrict__ fb16,    // [num_in*32] bf16
    const short* __restrict__ wpack,   // [K*64*16] bf16 frag-order
    const float* __restrict__ bias,
    const u32* __restrict__ pairs,
    const u32* __restrict__ off,
    float* __restrict__ out,
    int K, int num_out)
{
    __shared__ float acc[WIN * ACC_STRIDE];
    const int tid = threadIdx.x;
    #pragma unroll
    for (int i = 0; i < (WIN * ACC_STRIDE) / 512; ++i)
        acc[tid + i * 512] = 0.f;
    __syncthreads();

    const int w = blockIdx.x;
    const int wid = tid >> 6;
    const int lane = tid & 63;
    const int q = lane >> 4;
    const int m = lane & 15;

    // wave owns whole k-segments: B loop-invariant, zero loads of B inside loop
    for (int k = wid; k < K; k += 8) {
        const int b = w * K + k;
        const u32 start = off[b];
        const int nGs = (int)((off[b + 1] - start) >> 4);
        if (nGs == 0) continue;
        const u32* __restrict__ pb = pairs + start;

        const bf16x8* wb = (const bf16x8*)wpack + ((size_t)k * 64 + lane) * 2;
        const bf16x8 b0 = wb[0];
        const bf16x8 b1 = wb[1];

        // prologue: load group 0's pair + feature row
        u32 pr_cur = pb[m];
        bf16x8 a_cur = *(const bf16x8*)(fb16 + (size_t)(pr_cur & INR_MASK) * 32 + q * 8);

        for (int t = 0; t < nGs; ++t) {
            // prefetch next group (pairs L1-sequential; feature random L2/L3)
            u32 pr_nxt = (KPAD << 19);
            bf16x8 a_nxt = a_cur;
            if (t + 1 < nGs) {
                pr_nxt = pb[(u32)(t + 1) * 16u + m];
                a_nxt = *(const bf16x8*)(fb16 + (size_t)(pr_nxt & INR_MASK) * 32 + q * 8);
            }

            f32x4 c0 = {0.f,0.f,0.f,0.f};
            f32x4 c1 = {0.f,0.f,0.f,0.f};
            c0 = __builtin_amdgcn_mfma_f32_16x16x32_bf16(a_cur, b0, c0, 0, 0, 0);
            c1 = __builtin_amdgcn_mfma_f32_16x16x32_bf16(a_cur, b1, c1, 0, 0, 0);

            // scatter D rows (entry q*4+j) into owned LDS window; pads (k=31) skipped.
            // garbage D rows from pad A-rows are never scattered (row e depends only
            // on A row e), so no zeroing of A is needed.
            #pragma unroll
            for (int j = 0; j < 4; ++j) {
                u32 prj = __shfl(pr_cur, q * 4 + j);
                if (((prj >> 19) & 31u) != KPAD) {
                    int lr = (int)(prj >> 24);
                    atomicAdd(&acc[lr * ACC_STRIDE + m],      c0[j]);
                    atomicAdd(&acc[lr * ACC_STRIDE + 16 + m], c1[j]);
                }
            }
            pr_cur = pr_nxt;
            a_cur = a_nxt;
        }
    }
    __syncthreads();

    // write window once: out = acc + bias
    #pragma unroll
    for (int i = 0; i < 4; ++i) {
        const int v = tid + i * 512;
        const int row = v >> 3;
        const int c4 = v & 7;
        const int o = w * WIN + row;
        if (o < num_out) {
            f32x4 val = *(const f32x4*)&acc[row * ACC_STRIDE + c4 * 4];
            f32x4 bs = ((const f32x4*)bias)[c4];
            val.x += bs.x; val.y += bs.y; val.z += bs.z; val.w += bs.w;
            ((f32x4*)out)[(size_t)o * 8 + c4] = val;
        }
    }
}

// ---------------- fallback (R2 path) ----------------

__global__ void bias_init_kernel(float* __restrict__ out, const float* __restrict__ bias,
                                 int total4) {
    int idx = blockIdx.x * blockDim.x + threadIdx.x;
    if (idx >= total4) return;
    ((float4*)out)[idx] = ((const float4*)bias)[idx & 7];
}

__global__ __launch_bounds__(256, 8) void scatter_conv_mfma(
    const float* __restrict__ features, const float* __restrict__ weight,
    const int* __restrict__ in_map, const int* __restrict__ out_map,
    float* __restrict__ out, int P, int groups)
{
    const int k = blockIdx.y;
    const size_t kP = (size_t)k * (size_t)P;
    const int lane = threadIdx.x & 63;
    const int q = lane >> 4;
    const int m = lane & 15;
    const float* __restrict__ wk = weight + (size_t)k * (CI * CO);
    bf16x8 b0, b1;
    #pragma unroll
    for (int j = 0; j < 8; ++j) {
        int kk = q * 8 + j;
        b0[j] = f2bf(wk[kk * CO + m]);
        b1[j] = f2bf(wk[kk * CO + 16 + m]);
    }
    const int gwave = (blockIdx.x * blockDim.x + threadIdx.x) >> 6;
    const int gstride = (gridDim.x * blockDim.x) >> 6;
    for (int g = gwave; g < groups; g += gstride) {
        const int pbase = g * 16;
        const int pm = pbase + m;
        const int r = (pm < P) ? in_map[kP + pm] : 0;
        const f32x4* frow = (const f32x4*)(features + (size_t)r * CI + q * 8);
        f32x4 v0 = frow[0];
        f32x4 v1 = frow[1];
        bf16x8 a;
        a[0]=f2bf(v0.x); a[1]=f2bf(v0.y); a[2]=f2bf(v0.z); a[3]=f2bf(v0.w);
        a[4]=f2bf(v1.x); a[5]=f2bf(v1.y); a[6]=f2bf(v1.z); a[7]=f2bf(v1.w);
        if (pm >= P) a = (bf16x8){0,0,0,0,0,0,0,0};
        f32x4 acc0 = {0.f,0.f,0.f,0.f};
        f32x4 acc1 = {0.f,0.f,0.f,0.f};
        acc0 = __builtin_amdgcn_mfma_f32_16x16x32_bf16(a, b0, acc0, 0, 0, 0);
        acc1 = __builtin_amdgcn_mfma_f32_16x16x32_bf16(a, b1, acc1, 0, 0, 0);
        #pragma unroll
        for (int j = 0; j < 4; ++j) {
            const int row = q * 4 + j;
            const int pr = pbase + row;
            if (pr < P) {
                const int o = out_map[kP + pr];
                float* base = out + (size_t)o * CO + m;
                unsafeAtomicAdd(base,      acc0[j]);
                unsafeAtomicAdd(base + 16, acc1[j]);
            }
        }
    }
}

// ---------------- launch ----------------

static inline size_t align256(size_t x) { return (x + 255) & ~(size_t)255; }

extern "C" void kernel_launch(void* const* d_in, const int* in_sizes, int n_in,
                              void* d_out, int out_size, void* d_ws, size_t ws_size,
                              hipStream_t stream) {
    const float* features = (const float*)d_in[0];
    const float* weight   = (const float*)d_in[1];
    const float* bias     = (const float*)d_in[2];
    const int*   in_map   = (const int*)d_in[3];
    const int*   out_map  = (const int*)d_in[4];

    const int K = in_sizes[1] / (CI * CO);           // 27
    const int P = in_sizes[3] / K;                   // 150000
    const int num_out = out_size / CO;               // 500000
    const int num_in  = in_sizes[0] / CI;            // 500000
    float* out = (float*)d_out;

    const size_t NBW = ((size_t)num_out + WIN - 1) / WIN;     // windows
    const size_t NB  = NBW * (size_t)K;                       // buckets
    const size_t total = (size_t)K * (size_t)P;
    const size_t CAP = total + 15 * NB;
    const int nblkA = (int)((NB + 255) / 256);

    // ws layout
    const size_t o_cnt   = 0;
    const size_t o_off   = align256(o_cnt + NB * 4);
    const size_t o_cur   = align256(o_off + (NB + 1) * 4);
    const size_t o_bsum  = align256(o_cur + NB * 4);
    const size_t o_pairs = align256(o_bsum + 256 * 4);
    const size_t o_fb16  = align256(o_pairs + CAP * 4);
    const size_t o_wpack = align256(o_fb16 + (size_t)num_in * CI * 2);
    const size_t need    = o_wpack + (size_t)32 * 64 * 16 * 2;

    const bool sortable = (ws_size >= need) && (K <= 30) &&
                          (num_in <= 0x80000) && (nblkA <= 256);

    if (!sortable) {
        int total4 = num_out * (CO / 4);
        hipLaunchKernelGGL(bias_init_kernel, dim3((total4 + 255) / 256), dim3(256), 0,
                           stream, out, bias, total4);
        const int groups = (P + 15) / 16;
        hipLaunchKernelGGL(scatter_conv_mfma, dim3(160, K), dim3(256), 0, stream,
                           features, weight, in_map, out_map, out, P, groups);
        return;
    }

    char* ws = (char*)d_ws;
    u32*   cnt    = (u32*)(ws + o_cnt);
    u32*   off    = (u32*)(ws + o_off);
    u32*   cursor = (u32*)(ws + o_cur);
    u32*   bsum   = (u32*)(ws + o_bsum);
    u32*   pairs  = (u32*)(ws + o_pairs);
    short* fb16   = (short*)(ws + o_fb16);
    short* wpack  = (short*)(ws + o_wpack);

    // prep (independent)
    hipLaunchKernelGGL(fill_u32_kernel, dim3(64), dim3(256), 0, stream, cnt, 0u, NB);
    hipLaunchKernelGGL(convert_features, dim3(2048), dim3(256), 0, stream,
                       features, fb16, (size_t)num_in * CI / 8);
    hipLaunchKernelGGL(prepack_weights, dim3((K * 128 + 255) / 256), dim3(256), 0, stream,
                       weight, wpack, K);

    // counting sort by (window, k)
    dim3 mgrid((P + 255) / 256, K);
    hipLaunchKernelGGL(hist_kernel, mgrid, dim3(256), 0, stream, out_map, cnt, P, K);
    hipLaunchKernelGGL(scan_local, dim3(nblkA), dim3(256), 0, stream, cnt, off, bsum, (int)NB);
    hipLaunchKernelGGL(scan_bsum, dim3(1), dim3(256), 0, stream, bsum, off, nblkA, (int)NB);
    hipLaunchKernelGGL(scan_add, dim3(nblkA), dim3(256), 0, stream, off, cursor, bsum, (int)NB);
    hipLaunchKernelGGL(scatter_kernel, mgrid, dim3(256), 0, stream,
                       out_map, in_map, cursor, pairs, P, K);
    hipLaunchKernelGGL(padfill_kernel, dim3(nblkA), dim3(256), 0, stream,
                       cnt, off, pairs, (int)NB);

    // compute
    hipLaunchKernelGGL(window_conv_kernel, dim3((u32)NBW), dim3(512), 0, stream,
                       fb16, wpack, bias, pairs, off, out, K, num_out);
}

// Round 6
// 430.292 us; speedup vs baseline: 3.1323x; 2.6158x over previous
//
#include <hip/hip_runtime.h>
#include <hip/hip_bf16.h>

#define CI 32
#define CO 32

typedef unsigned int u32;
typedef __attribute__((ext_vector_type(8))) short bf16x8;
typedef __attribute__((ext_vector_type(4))) float f32x4;

__device__ inline short f2bf(float x) {
    __hip_bfloat16 h = __float2bfloat16(x);
    return *reinterpret_cast<short*>(&h);
}

// ---------------- prep ----------------

// features fp32 -> bf16: each row becomes ONE 64B line (halves random-gather lines)
__global__ void convert_features(const float* __restrict__ f, short* __restrict__ fb,
                                 size_t n8) {
    size_t i = (size_t)blockIdx.x * blockDim.x + threadIdx.x;
    size_t stride = (size_t)gridDim.x * blockDim.x;
    for (; i < n8; i += stride) {
        const f32x4* src = (const f32x4*)(f + i * 8);
        f32x4 v0 = src[0], v1 = src[1];
        bf16x8 o;
        o[0]=f2bf(v0.x); o[1]=f2bf(v0.y); o[2]=f2bf(v0.z); o[3]=f2bf(v0.w);
        o[4]=f2bf(v1.x); o[5]=f2bf(v1.y); o[6]=f2bf(v1.z); o[7]=f2bf(v1.w);
        ((bf16x8*)fb)[i] = o;
    }
}

__global__ void bias_init_kernel(float* __restrict__ out, const float* __restrict__ bias,
                                 int total4) {
    int idx = blockIdx.x * blockDim.x + threadIdx.x;
    if (idx >= total4) return;
    ((float4*)out)[idx] = ((const float4*)bias)[idx & 7];
}

// ---------------- main: gather(bf16) -> MFMA -> fire-and-forget atomic scatter ----------------
// R2 structure (measured: fabric-byte-bound at ~1.85 TB/s). bf16 gather halves fetch lines.

__global__ __launch_bounds__(256, 8) void scatter_conv_bf16(
    const short* __restrict__ fb16,     // [num_in][32] bf16 rows (64B each)
    const float* __restrict__ weight,
    const int* __restrict__ in_map,
    const int* __restrict__ out_map,
    float* __restrict__ out,
    int P, int groups)
{
    const int k = blockIdx.y;
    const size_t kP = (size_t)k * (size_t)P;
    const int lane = threadIdx.x & 63;
    const int q = lane >> 4;        // k-chunk quarter
    const int m = lane & 15;        // A-row within group / D column

    // B fragments: loop-invariant, built once per wave from fp32 weights
    const float* __restrict__ wk = weight + (size_t)k * (CI * CO);
    bf16x8 b0, b1;
    #pragma unroll
    for (int j = 0; j < 8; ++j) {
        int kk = q * 8 + j;
        b0[j] = f2bf(wk[kk * CO + m]);
        b1[j] = f2bf(wk[kk * CO + 16 + m]);
    }

    const int gwave   = (blockIdx.x * blockDim.x + threadIdx.x) >> 6;
    const int gstride = (gridDim.x * blockDim.x) >> 6;

    for (int g = gwave; g < groups; g += gstride) {
        const int pbase = g * 16;
        const int pm = pbase + m;

        // gather A: one 16B chunk of the row's single 64B line per lane
        const int r = (pm < P) ? in_map[kP + pm] : 0;
        bf16x8 a = *(const bf16x8*)(fb16 + (size_t)r * CI + q * 8);
        if (pm >= P) a = (bf16x8){0,0,0,0,0,0,0,0};

        f32x4 acc0 = {0.f,0.f,0.f,0.f};
        f32x4 acc1 = {0.f,0.f,0.f,0.f};
        acc0 = __builtin_amdgcn_mfma_f32_16x16x32_bf16(a, b0, acc0, 0, 0, 0);
        acc1 = __builtin_amdgcn_mfma_f32_16x16x32_bf16(a, b1, acc1, 0, 0, 0);

        // scatter: D row=(q*4+j), col=m. Fire-and-forget atomics (~1.85 TB/s side).
        #pragma unroll
        for (int j = 0; j < 4; ++j) {
            const int row = q * 4 + j;
            const int pr = pbase + row;
            if (pr < P) {
                const int o = out_map[kP + pr];
                float* base = out + (size_t)o * CO + m;
                unsafeAtomicAdd(base,      acc0[j]);
                unsafeAtomicAdd(base + 16, acc1[j]);
            }
        }
    }
}

// ---------------- fallback: R2 exact path (fp32 gather inline) ----------------

__global__ __launch_bounds__(256, 8) void scatter_conv_mfma(
    const float* __restrict__ features, const float* __restrict__ weight,
    const int* __restrict__ in_map, const int* __restrict__ out_map,
    float* __restrict__ out, int P, int groups)
{
    const int k = blockIdx.y;
    const size_t kP = (size_t)k * (size_t)P;
    const int lane = threadIdx.x & 63;
    const int q = lane >> 4;
    const int m = lane & 15;
    const float* __restrict__ wk = weight + (size_t)k * (CI * CO);
    bf16x8 b0, b1;
    #pragma unroll
    for (int j = 0; j < 8; ++j) {
        int kk = q * 8 + j;
        b0[j] = f2bf(wk[kk * CO + m]);
        b1[j] = f2bf(wk[kk * CO + 16 + m]);
    }
    const int gwave = (blockIdx.x * blockDim.x + threadIdx.x) >> 6;
    const int gstride = (gridDim.x * blockDim.x) >> 6;
    for (int g = gwave; g < groups; g += gstride) {
        const int pbase = g * 16;
        const int pm = pbase + m;
        const int r = (pm < P) ? in_map[kP + pm] : 0;
        const f32x4* frow = (const f32x4*)(features + (size_t)r * CI + q * 8);
        f32x4 v0 = frow[0];
        f32x4 v1 = frow[1];
        bf16x8 a;
        a[0]=f2bf(v0.x); a[1]=f2bf(v0.y); a[2]=f2bf(v0.z); a[3]=f2bf(v0.w);
        a[4]=f2bf(v1.x); a[5]=f2bf(v1.y); a[6]=f2bf(v1.z); a[7]=f2bf(v1.w);
        if (pm >= P) a = (bf16x8){0,0,0,0,0,0,0,0};
        f32x4 acc0 = {0.f,0.f,0.f,0.f};
        f32x4 acc1 = {0.f,0.f,0.f,0.f};
        acc0 = __builtin_amdgcn_mfma_f32_16x16x32_bf16(a, b0, acc0, 0, 0, 0);
        acc1 = __builtin_amdgcn_mfma_f32_16x16x32_bf16(a, b1, acc1, 0, 0, 0);
        #pragma unroll
        for (int j = 0; j < 4; ++j) {
            const int row = q * 4 + j;
            const int pr = pbase + row;
            if (pr < P) {
                const int o = out_map[kP + pr];
                float* base = out + (size_t)o * CO + m;
                unsafeAtomicAdd(base,      acc0[j]);
                unsafeAtomicAdd(base + 16, acc1[j]);
            }
        }
    }
}

// ---------------- launch ----------------

extern "C" void kernel_launch(void* const* d_in, const int* in_sizes, int n_in,
                              void* d_out, int out_size, void* d_ws, size_t ws_size,
                              hipStream_t stream) {
    const float* features = (const float*)d_in[0];
    const float* weight   = (const float*)d_in[1];
    const float* bias     = (const float*)d_in[2];
    const int*   in_map   = (const int*)d_in[3];
    const int*   out_map  = (const int*)d_in[4];

    const int K = in_sizes[1] / (CI * CO);           // 27
    const int P = in_sizes[3] / K;                   // 150000
    const int num_out = out_size / CO;               // 500000
    const int num_in  = in_sizes[0] / CI;            // 500000
    float* out = (float*)d_out;

    const int groups = (P + 15) / 16;                // 9375

    // 1) init with bias (atomics accumulate on top)
    {
        int total4 = num_out * (CO / 4);
        hipLaunchKernelGGL(bias_init_kernel, dim3((total4 + 255) / 256), dim3(256), 0,
                           stream, out, bias, total4);
    }

    const size_t fb_bytes = (size_t)num_in * CI * 2;
    if (ws_size >= fb_bytes) {
        short* fb16 = (short*)d_ws;
        // 2) pre-convert features to bf16 (64B rows -> half the random-gather lines)
        hipLaunchKernelGGL(convert_features, dim3(2048), dim3(256), 0, stream,
                           features, fb16, (size_t)num_in * CI / 8);
        // 3) gather-MFMA-scatter
        hipLaunchKernelGGL(scatter_conv_bf16, dim3(256, K), dim3(256), 0, stream,
                           fb16, weight, in_map, out_map, out, P, groups);
    } else {
        hipLaunchKernelGGL(scatter_conv_mfma, dim3(256, K), dim3(256), 0, stream,
                           features, weight, in_map, out_map, out, P, groups);
    }
}

// Round 7
// 255.541 us; speedup vs baseline: 5.2743x; 1.6839x over previous
//
#include <hip/hip_runtime.h>
#include <hip/hip_bf16.h>
#include <hip/hip_fp16.h>

#define CI 32
#define CO 32

typedef unsigned int u32;
typedef __attribute__((ext_vector_type(8))) short bf16x8;
typedef __attribute__((ext_vector_type(4))) float f32x4;
typedef __attribute__((ext_vector_type(4))) u32 u32x4;

__device__ inline short f2bf(float x) {
    __hip_bfloat16 h = __float2bfloat16(x);
    return *reinterpret_cast<short*>(&h);
}

// ---------------- prep ----------------

// features fp32 -> bf16: each row becomes ONE 64B line
__global__ void convert_features(const float* __restrict__ f, short* __restrict__ fb,
                                 size_t n8) {
    size_t i = (size_t)blockIdx.x * blockDim.x + threadIdx.x;
    size_t stride = (size_t)gridDim.x * blockDim.x;
    for (; i < n8; i += stride) {
        const f32x4* src = (const f32x4*)(f + i * 8);
        f32x4 v0 = src[0], v1 = src[1];
        bf16x8 o;
        o[0]=f2bf(v0.x); o[1]=f2bf(v0.y); o[2]=f2bf(v0.z); o[3]=f2bf(v0.w);
        o[4]=f2bf(v1.x); o[5]=f2bf(v1.y); o[6]=f2bf(v1.z); o[7]=f2bf(v1.w);
        ((bf16x8*)fb)[i] = o;
    }
}

__global__ void zero_ws_kernel(u32x4* __restrict__ p, size_t n4) {
    size_t i = (size_t)blockIdx.x * blockDim.x + threadIdx.x;
    size_t stride = (size_t)gridDim.x * blockDim.x;
    u32x4 z = {0u, 0u, 0u, 0u};
    for (; i < n4; i += stride) p[i] = z;
}

// ---------------- main: gather(bf16) -> MFMA -> packed-f16 atomic scatter ----------------
// wsacc row layout (64B = 1 line): __half2 slot m = channels (m, m+16).
// One pk_add_f16 per lane -> 16 lanes cover the full row line; 1 RMW line/entry
// (vs 2 for fp32), halving the dominant fabric line-op term.

__global__ __launch_bounds__(256, 8) void scatter_conv_f16acc(
    const short* __restrict__ fb16,     // [num_in][32] bf16 rows (64B each)
    const float* __restrict__ weight,
    const int* __restrict__ in_map,
    const int* __restrict__ out_map,
    __half2* __restrict__ wsacc,        // [num_out][16] __half2
    int P, int groups)
{
    const int k = blockIdx.y;
    const size_t kP = (size_t)k * (size_t)P;
    const int lane = threadIdx.x & 63;
    const int q = lane >> 4;        // k-chunk quarter / D-row group
    const int m = lane & 15;        // A-row within group / D column

    // B fragments: loop-invariant
    const float* __restrict__ wk = weight + (size_t)k * (CI * CO);
    bf16x8 b0, b1;
    #pragma unroll
    for (int j = 0; j < 8; ++j) {
        int kk = q * 8 + j;
        b0[j] = f2bf(wk[kk * CO + m]);
        b1[j] = f2bf(wk[kk * CO + 16 + m]);
    }

    const int gwave   = (blockIdx.x * blockDim.x + threadIdx.x) >> 6;
    const int gstride = (gridDim.x * blockDim.x) >> 6;

    for (int g = gwave; g < groups; g += gstride) {
        const int pbase = g * 16;
        const int pm = pbase + m;

        // gather A: one 16B chunk of the row's single 64B line per lane
        const int r = (pm < P) ? in_map[kP + pm] : 0;
        bf16x8 a = *(const bf16x8*)(fb16 + (size_t)r * CI + q * 8);
        if (pm >= P) a = (bf16x8){0,0,0,0,0,0,0,0};

        f32x4 acc0 = {0.f,0.f,0.f,0.f};   // channels m      (B cols 0-15)
        f32x4 acc1 = {0.f,0.f,0.f,0.f};   // channels m+16   (B cols 16-31)
        acc0 = __builtin_amdgcn_mfma_f32_16x16x32_bf16(a, b0, acc0, 0, 0, 0);
        acc1 = __builtin_amdgcn_mfma_f32_16x16x32_bf16(a, b1, acc1, 0, 0, 0);

        // scatter: D row=(q*4+j), lane owns channel pair (m, m+16) -> one pk atomic
        #pragma unroll
        for (int j = 0; j < 4; ++j) {
            const int row = q * 4 + j;
            const int pr = pbase + row;
            if (pr < P) {
                const int o = out_map[kP + pr];
                __half2 v = __floats2half2_rn(acc0[j], acc1[j]);
                unsafeAtomicAdd(&wsacc[(size_t)o * 16 + m], v);
            }
        }
    }
}

// ---------------- finalize: out = fp32(wsacc) + bias (un-permute channels) ----------------

__global__ void finalize_kernel(const __half2* __restrict__ wsacc,
                                const float* __restrict__ bias,
                                float* __restrict__ out, int num_out) {
    int o = blockIdx.x * blockDim.x + threadIdx.x;
    if (o >= num_out) return;
    const __half2* wr = wsacc + (size_t)o * 16;
    float vals[32];
    #pragma unroll
    for (int i = 0; i < 16; ++i) {
        float2 f = __half22float2(wr[i]);
        vals[i]      = f.x + bias[i];
        vals[i + 16] = f.y + bias[i + 16];
    }
    #pragma unroll
    for (int i = 0; i < 8; ++i)
        ((float4*)out)[(size_t)o * 8 + i] = *(float4*)&vals[i * 4];
}

// ---------------- fallback: R6 fp32-atomic path ----------------

__global__ void bias_init_kernel(float* __restrict__ out, const float* __restrict__ bias,
                                 int total4) {
    int idx = blockIdx.x * blockDim.x + threadIdx.x;
    if (idx >= total4) return;
    ((float4*)out)[idx] = ((const float4*)bias)[idx & 7];
}

__global__ __launch_bounds__(256, 8) void scatter_conv_mfma(
    const float* __restrict__ features, const float* __restrict__ weight,
    const int* __restrict__ in_map, const int* __restrict__ out_map,
    float* __restrict__ out, int P, int groups)
{
    const int k = blockIdx.y;
    const size_t kP = (size_t)k * (size_t)P;
    const int lane = threadIdx.x & 63;
    const int q = lane >> 4;
    const int m = lane & 15;
    const float* __restrict__ wk = weight + (size_t)k * (CI * CO);
    bf16x8 b0, b1;
    #pragma unroll
    for (int j = 0; j < 8; ++j) {
        int kk = q * 8 + j;
        b0[j] = f2bf(wk[kk * CO + m]);
        b1[j] = f2bf(wk[kk * CO + 16 + m]);
    }
    const int gwave = (blockIdx.x * blockDim.x + threadIdx.x) >> 6;
    const int gstride = (gridDim.x * blockDim.x) >> 6;
    for (int g = gwave; g < groups; g += gstride) {
        const int pbase = g * 16;
        const int pm = pbase + m;
        const int r = (pm < P) ? in_map[kP + pm] : 0;
        const f32x4* frow = (const f32x4*)(features + (size_t)r * CI + q * 8);
        f32x4 v0 = frow[0];
        f32x4 v1 = frow[1];
        bf16x8 a;
        a[0]=f2bf(v0.x); a[1]=f2bf(v0.y); a[2]=f2bf(v0.z); a[3]=f2bf(v0.w);
        a[4]=f2bf(v1.x); a[5]=f2bf(v1.y); a[6]=f2bf(v1.z); a[7]=f2bf(v1.w);
        if (pm >= P) a = (bf16x8){0,0,0,0,0,0,0,0};
        f32x4 acc0 = {0.f,0.f,0.f,0.f};
        f32x4 acc1 = {0.f,0.f,0.f,0.f};
        acc0 = __builtin_amdgcn_mfma_f32_16x16x32_bf16(a, b0, acc0, 0, 0, 0);
        acc1 = __builtin_amdgcn_mfma_f32_16x16x32_bf16(a, b1, acc1, 0, 0, 0);
        #pragma unroll
        for (int j = 0; j < 4; ++j) {
            const int row = q * 4 + j;
            const int pr = pbase + row;
            if (pr < P) {
                const int o = out_map[kP + pr];
                float* base = out + (size_t)o * CO + m;
                unsafeAtomicAdd(base,      acc0[j]);
                unsafeAtomicAdd(base + 16, acc1[j]);
            }
        }
    }
}

// ---------------- launch ----------------

static inline size_t align256(size_t x) { return (x + 255) & ~(size_t)255; }

extern "C" void kernel_launch(void* const* d_in, const int* in_sizes, int n_in,
                              void* d_out, int out_size, void* d_ws, size_t ws_size,
                              hipStream_t stream) {
    const float* features = (const float*)d_in[0];
    const float* weight   = (const float*)d_in[1];
    const float* bias     = (const float*)d_in[2];
    const int*   in_map   = (const int*)d_in[3];
    const int*   out_map  = (const int*)d_in[4];

    const int K = in_sizes[1] / (CI * CO);           // 27
    const int P = in_sizes[3] / K;                   // 150000
    const int num_out = out_size / CO;               // 500000
    const int num_in  = in_sizes[0] / CI;            // 500000
    float* out = (float*)d_out;

    const int groups = (P + 15) / 16;                // 9375

    const size_t o_fb   = 0;
    const size_t o_acc  = align256(o_fb + (size_t)num_in * CI * 2);
    const size_t need   = o_acc + (size_t)num_out * CO * 2;

    if (ws_size >= need) {
        short*   fb16  = (short*)((char*)d_ws + o_fb);
        __half2* wsacc = (__half2*)((char*)d_ws + o_acc);

        // prep: bf16 features + zeroed f16 accumulator (both every call)
        hipLaunchKernelGGL(convert_features, dim3(2048), dim3(256), 0, stream,
                           features, fb16, (size_t)num_in * CI / 8);
        hipLaunchKernelGGL(zero_ws_kernel, dim3(2048), dim3(256), 0, stream,
                           (u32x4*)wsacc, (size_t)num_out * CO * 2 / 16);

        // gather-MFMA-scatter (packed f16 atomics: 1 RMW line per entry)
        hipLaunchKernelGGL(scatter_conv_f16acc, dim3(256, K), dim3(256), 0, stream,
                           fb16, weight, in_map, out_map, wsacc, P, groups);

        // finalize: un-permute channels, add bias, fp32 out
        hipLaunchKernelGGL(finalize_kernel, dim3((num_out + 255) / 256), dim3(256), 0,
                           stream, wsacc, bias, out, num_out);
    } else {
        int total4 = num_out * (CO / 4);
        hipLaunchKernelGGL(bias_init_kernel, dim3((total4 + 255) / 256), dim3(256), 0,
                           stream, out, bias, total4);
        hipLaunchKernelGGL(scatter_conv_mfma, dim3(256, K), dim3(256), 0, stream,
                           features, weight, in_map, out_map, out, P, groups);
    }
}

// Round 8
// 252.534 us; speedup vs baseline: 5.3371x; 1.0119x over previous
//
#include <hip/hip_runtime.h>
#include <hip/hip_bf16.h>
#include <hip/hip_fp16.h>

#define CI 32
#define CO 32

typedef unsigned int u32;
typedef __attribute__((ext_vector_type(8))) short bf16x8;
typedef __attribute__((ext_vector_type(4))) float f32x4;
typedef __attribute__((ext_vector_type(4))) u32 u32x4;

__device__ inline short f2bf(float x) {
    __hip_bfloat16 h = __float2bfloat16(x);
    return *reinterpret_cast<short*>(&h);
}

// ---------------- prep: fused (features fp32->bf16) + (zero f16 accumulator) ----------------
// one launch, both ranges coalesced; saves a launch gap vs two kernels.

__global__ void prep_kernel(const float* __restrict__ f, short* __restrict__ fb,
                            u32x4* __restrict__ wsz, size_t nf8, size_t nz4) {
    size_t i = (size_t)blockIdx.x * blockDim.x + threadIdx.x;
    size_t stride = (size_t)gridDim.x * blockDim.x;
    size_t total = nf8 + nz4;
    u32x4 z = {0u, 0u, 0u, 0u};
    for (; i < total; i += stride) {
        if (i < nf8) {
            const f32x4* src = (const f32x4*)(f + i * 8);
            f32x4 v0 = src[0], v1 = src[1];
            bf16x8 o;
            o[0]=f2bf(v0.x); o[1]=f2bf(v0.y); o[2]=f2bf(v0.z); o[3]=f2bf(v0.w);
            o[4]=f2bf(v1.x); o[5]=f2bf(v1.y); o[6]=f2bf(v1.z); o[7]=f2bf(v1.w);
            ((bf16x8*)fb)[i] = o;
        } else {
            wsz[i - nf8] = z;
        }
    }
}

// ---------------- main: gather(bf16) -> MFMA -> packed-f16 atomic scatter ----------------
// wsacc row (64B = 1 fabric line): __half2 slot m = channels (m, m+16).
// Floor analysis (R2..R7 measured): 4.05M random gather lines + 4.05M RMW lines
// at ~39 G lines/s fabric random service rate => ~210 us. This kernel sits on it.

__global__ __launch_bounds__(256, 8) void scatter_conv_f16acc(
    const short* __restrict__ fb16,     // [num_in][32] bf16 rows (64B each)
    const float* __restrict__ weight,
    const int* __restrict__ in_map,
    const int* __restrict__ out_map,
    __half2* __restrict__ wsacc,        // [num_out][16] __half2
    int P, int groups)
{
    const int k = blockIdx.y;
    const size_t kP = (size_t)k * (size_t)P;
    const int lane = threadIdx.x & 63;
    const int q = lane >> 4;        // k-chunk quarter / D-row group
    const int m = lane & 15;        // A-row within group / D column

    // B fragments: loop-invariant
    const float* __restrict__ wk = weight + (size_t)k * (CI * CO);
    bf16x8 b0, b1;
    #pragma unroll
    for (int j = 0; j < 8; ++j) {
        int kk = q * 8 + j;
        b0[j] = f2bf(wk[kk * CO + m]);
        b1[j] = f2bf(wk[kk * CO + 16 + m]);
    }

    const int gwave   = (blockIdx.x * blockDim.x + threadIdx.x) >> 6;
    const int gstride = (gridDim.x * blockDim.x) >> 6;

    for (int g = gwave; g < groups; g += gstride) {
        const int pbase = g * 16;
        const int pm = pbase + m;

        // gather A: one 16B chunk of the row's single 64B line per lane
        const int r = (pm < P) ? in_map[kP + pm] : 0;
        bf16x8 a = *(const bf16x8*)(fb16 + (size_t)r * CI + q * 8);
        if (pm >= P) a = (bf16x8){0,0,0,0,0,0,0,0};

        f32x4 acc0 = {0.f,0.f,0.f,0.f};   // channels m      (B cols 0-15)
        f32x4 acc1 = {0.f,0.f,0.f,0.f};   // channels m+16   (B cols 16-31)
        acc0 = __builtin_amdgcn_mfma_f32_16x16x32_bf16(a, b0, acc0, 0, 0, 0);
        acc1 = __builtin_amdgcn_mfma_f32_16x16x32_bf16(a, b1, acc1, 0, 0, 0);

        // scatter: D row=(q*4+j); lane owns channel pair (m, m+16) -> one pk atomic;
        // 16 lanes cover the row's full 64B line -> 1 RMW line per entry.
        #pragma unroll
        for (int j = 0; j < 4; ++j) {
            const int row = q * 4 + j;
            const int pr = pbase + row;
            if (pr < P) {
                const int o = out_map[kP + pr];
                __half2 v = __floats2half2_rn(acc0[j], acc1[j]);
                unsafeAtomicAdd(&wsacc[(size_t)o * 16 + m], v);
            }
        }
    }
}

// ---------------- finalize: out = fp32(wsacc) + bias (un-permute channels) ----------------

__global__ void finalize_kernel(const __half2* __restrict__ wsacc,
                                const float* __restrict__ bias,
                                float* __restrict__ out, int num_out) {
    int o = blockIdx.x * blockDim.x + threadIdx.x;
    if (o >= num_out) return;
    const __half2* wr = wsacc + (size_t)o * 16;
    float vals[32];
    #pragma unroll
    for (int i = 0; i < 16; ++i) {
        float2 f = __half22float2(wr[i]);
        vals[i]      = f.x + bias[i];
        vals[i + 16] = f.y + bias[i + 16];
    }
    #pragma unroll
    for (int i = 0; i < 8; ++i)
        ((float4*)out)[(size_t)o * 8 + i] = *(float4*)&vals[i * 4];
}

// ---------------- fallback: fp32-atomic path (no workspace needed) ----------------

__global__ void bias_init_kernel(float* __restrict__ out, const float* __restrict__ bias,
                                 int total4) {
    int idx = blockIdx.x * blockDim.x + threadIdx.x;
    if (idx >= total4) return;
    ((float4*)out)[idx] = ((const float4*)bias)[idx & 7];
}

__global__ __launch_bounds__(256, 8) void scatter_conv_mfma(
    const float* __restrict__ features, const float* __restrict__ weight,
    const int* __restrict__ in_map, const int* __restrict__ out_map,
    float* __restrict__ out, int P, int groups)
{
    const int k = blockIdx.y;
    const size_t kP = (size_t)k * (size_t)P;
    const int lane = threadIdx.x & 63;
    const int q = lane >> 4;
    const int m = lane & 15;
    const float* __restrict__ wk = weight + (size_t)k * (CI * CO);
    bf16x8 b0, b1;
    #pragma unroll
    for (int j = 0; j < 8; ++j) {
        int kk = q * 8 + j;
        b0[j] = f2bf(wk[kk * CO + m]);
        b1[j] = f2bf(wk[kk * CO + 16 + m]);
    }
    const int gwave = (blockIdx.x * blockDim.x + threadIdx.x) >> 6;
    const int gstride = (gridDim.x * blockDim.x) >> 6;
    for (int g = gwave; g < groups; g += gstride) {
        const int pbase = g * 16;
        const int pm = pbase + m;
        const int r = (pm < P) ? in_map[kP + pm] : 0;
        const f32x4* frow = (const f32x4*)(features + (size_t)r * CI + q * 8);
        f32x4 v0 = frow[0];
        f32x4 v1 = frow[1];
        bf16x8 a;
        a[0]=f2bf(v0.x); a[1]=f2bf(v0.y); a[2]=f2bf(v0.z); a[3]=f2bf(v0.w);
        a[4]=f2bf(v1.x); a[5]=f2bf(v1.y); a[6]=f2bf(v1.z); a[7]=f2bf(v1.w);
        if (pm >= P) a = (bf16x8){0,0,0,0,0,0,0,0};
        f32x4 acc0 = {0.f,0.f,0.f,0.f};
        f32x4 acc1 = {0.f,0.f,0.f,0.f};
        acc0 = __builtin_amdgcn_mfma_f32_16x16x32_bf16(a, b0, acc0, 0, 0, 0);
        acc1 = __builtin_amdgcn_mfma_f32_16x16x32_bf16(a, b1, acc1, 0, 0, 0);
        #pragma unroll
        for (int j = 0; j < 4; ++j) {
            const int row = q * 4 + j;
            const int pr = pbase + row;
            if (pr < P) {
                const int o = out_map[kP + pr];
                float* base = out + (size_t)o * CO + m;
                unsafeAtomicAdd(base,      acc0[j]);
                unsafeAtomicAdd(base + 16, acc1[j]);
            }
        }
    }
}

// ---------------- launch ----------------

static inline size_t align256(size_t x) { return (x + 255) & ~(size_t)255; }

extern "C" void kernel_launch(void* const* d_in, const int* in_sizes, int n_in,
                              void* d_out, int out_size, void* d_ws, size_t ws_size,
                              hipStream_t stream) {
    const float* features = (const float*)d_in[0];
    const float* weight   = (const float*)d_in[1];
    const float* bias     = (const float*)d_in[2];
    const int*   in_map   = (const int*)d_in[3];
    const int*   out_map  = (const int*)d_in[4];

    const int K = in_sizes[1] / (CI * CO);           // 27
    const int P = in_sizes[3] / K;                   // 150000
    const int num_out = out_size / CO;               // 500000
    const int num_in  = in_sizes[0] / CI;            // 500000
    float* out = (float*)d_out;

    const int groups = (P + 15) / 16;                // 9375

    const size_t o_fb   = 0;
    const size_t o_acc  = align256(o_fb + (size_t)num_in * CI * 2);
    const size_t need   = o_acc + (size_t)num_out * CO * 2;

    if (ws_size >= need) {
        short*   fb16  = (short*)((char*)d_ws + o_fb);
        __half2* wsacc = (__half2*)((char*)d_ws + o_acc);

        // prep (fused): bf16 features + zeroed f16 accumulator
        const size_t nf8 = (size_t)num_in * CI / 8;
        const size_t nz4 = (size_t)num_out * CO * 2 / 16;
        hipLaunchKernelGGL(prep_kernel, dim3(4096), dim3(256), 0, stream,
                           features, fb16, (u32x4*)wsacc, nf8, nz4);

        // gather-MFMA-scatter (packed f16 atomics: 1 RMW line per entry)
        hipLaunchKernelGGL(scatter_conv_f16acc, dim3(256, K), dim3(256), 0, stream,
                           fb16, weight, in_map, out_map, wsacc, P, groups);

        // finalize: un-permute channels, add bias, fp32 out
        hipLaunchKernelGGL(finalize_kernel, dim3((num_out + 255) / 256), dim3(256), 0,
                           stream, wsacc, bias, out, num_out);
    } else {
        int total4 = num_out * (CO / 4);
        hipLaunchKernelGGL(bias_init_kernel, dim3((total4 + 255) / 256), dim3(256), 0,
                           stream, out, bias, total4);
        hipLaunchKernelGGL(scatter_conv_mfma, dim3(256, K), dim3(256), 0, stream,
                           features, weight, in_map, out_map, out, P, groups);
    }
}